// Round 17
// baseline (118.851 us; speedup 1.0000x reference)
//
#include <hip/hip_runtime.h>
#include <hip/hip_fp16.h>
#include <math.h>

#define N_NODES 50000
#define N_EDGES 1000000
#define N_HID 64
#define N_GRAPHS 500
#define IN_DIM 4
#define NPAD 50048
#define SRC_SPLIT 25000

#define BK_SHIFT 7
#define BK_NODES 128                      // nodes per bucket
#define NBUCK 391                         // ceil(50000/128)
#define BCAP 3072                         // mean 2560 + 10 sigma
#define EPT 16                            // edges per thread in k_bin
#define EPW (EPT * 256)                   // 4096 edges per WG
#define NWG_BIN ((N_EDGES + EPW - 1) / EPW)

typedef float nt_f4 __attribute__((ext_vector_type(4)));

// ---------- init: bcur, gstart/gend, pooled sums ----------
__global__ void k_init(int* bcur, int* gstart, int* gend, float* sums) {
    int i = blockIdx.x * blockDim.x + threadIdx.x;
    if (i < 512) { bcur[i] = 0; gstart[i] = 0; gend[i] = 0; }
    if (i < N_GRAPHS * N_HID) sums[i] = 0.f;
}

// ---------- pass A: bin packed (src<<7|dstlocal) by dst bucket ----------
__global__ void k_bin(const int* __restrict__ ei, int* bcur, int* __restrict__ P) {
    __shared__ int hist[NBUCK];
    __shared__ int base[NBUCK];
    int t = threadIdx.x;
    int wg0 = blockIdx.x * EPW;
    for (int b = t; b < NBUCK; b += 256) hist[b] = 0;
    __syncthreads();

    const int4* s4 = (const int4*)ei;
    const int4* d4 = (const int4*)(ei + N_EDGES);
    int rs[EPT], rd[EPT], rl[EPT];
#pragma unroll
    for (int i = 0; i < 4; ++i) {
        int e = wg0 + (i * 256 + t) * 4;
        if (e < N_EDGES) {
            int4 vs = s4[e >> 2];
            int4 vd = d4[e >> 2];
            rs[i * 4 + 0] = vs.x; rd[i * 4 + 0] = vd.x;
            rs[i * 4 + 1] = vs.y; rd[i * 4 + 1] = vd.y;
            rs[i * 4 + 2] = vs.z; rd[i * 4 + 2] = vd.z;
            rs[i * 4 + 3] = vs.w; rd[i * 4 + 3] = vd.w;
            rl[i * 4 + 0] = atomicAdd(&hist[vd.x >> BK_SHIFT], 1);
            rl[i * 4 + 1] = atomicAdd(&hist[vd.y >> BK_SHIFT], 1);
            rl[i * 4 + 2] = atomicAdd(&hist[vd.z >> BK_SHIFT], 1);
            rl[i * 4 + 3] = atomicAdd(&hist[vd.w >> BK_SHIFT], 1);
        } else {
            rd[i * 4 + 0] = rd[i * 4 + 1] = rd[i * 4 + 2] = rd[i * 4 + 3] = -1;
        }
    }
    __syncthreads();
    for (int b = t; b < NBUCK; b += 256) {
        int h = hist[b];
        base[b] = h ? atomicAdd(&bcur[b], h) : 0;
    }
    __syncthreads();
#pragma unroll
    for (int i = 0; i < EPT; ++i) {
        if (rd[i] >= 0) {
            int bk = rd[i] >> BK_SHIFT;
            int loc = base[bk] + rl[i];
            if (loc > BCAP - 1) loc = BCAP - 1;   // overflow guard (never expected)
            P[(size_t)bk * BCAP + loc] = (rs[i] << BK_SHIFT) | (rd[i] & (BK_NODES - 1));
        }
    }
}

// ---------- pass B: counting sort + src-partition -> CSR rows + mid + dis + xs ----
__global__ void k_build(const int* __restrict__ bcur, const int* __restrict__ P,
                        const float* __restrict__ x,
                        int* __restrict__ srcidx, int* __restrict__ offs,
                        int* __restrict__ mid, int* __restrict__ endp,
                        float* __restrict__ dis, float* __restrict__ xs) {
    __shared__ int sp[BCAP];
    __shared__ int scnt[BK_NODES];
    __shared__ int scntLo[BK_NODES];
    __shared__ int sscan[BK_NODES];
    __shared__ int scurLo[BK_NODES];
    __shared__ int scurHi[BK_NODES];
    int b = blockIdx.x;
    int t = threadIdx.x;
    int n = bcur[b];
    if (n > BCAP) n = BCAP;
    if (t < BK_NODES) { scnt[t] = 0; scntLo[t] = 0; }
    __syncthreads();
    for (int i = t; i < n; i += 256) {
        int v = P[(size_t)b * BCAP + i];
        sp[i] = v;
        int ln = v & (BK_NODES - 1);
        atomicAdd(&scnt[ln], 1);
        if ((v >> BK_SHIFT) < SRC_SPLIT) atomicAdd(&scntLo[ln], 1);
    }
    __syncthreads();
    if (t < BK_NODES) sscan[t] = scnt[t];
    __syncthreads();
    for (int d = 1; d < BK_NODES; d <<= 1) {
        int v = 0;
        if (t < BK_NODES && t >= d) v = sscan[t - d];
        __syncthreads();
        if (t < BK_NODES) sscan[t] += v;
        __syncthreads();
    }
    if (t < BK_NODES) {
        int excl = sscan[t] - scnt[t];
        scurLo[t] = excl;
        scurHi[t] = excl + scntLo[t];
        int node = b * BK_NODES + t;
        if (node < N_NODES) {
            int o = b * BCAP + excl;
            offs[node] = o;
            mid[node] = o + scntLo[t];
            endp[node] = o + scnt[t];
            float dd = 1.0f / sqrtf((float)(scnt[t] + 1));
            dis[node] = dd;
            float4 xv = ((const float4*)x)[node];
            xv.x *= dd; xv.y *= dd; xv.z *= dd; xv.w *= dd;
            ((float4*)xs)[node] = xv;
        }
    }
    __syncthreads();
    for (int i = t; i < n; i += 256) {
        int v = sp[i];
        int ln = v & (BK_NODES - 1);
        int src = v >> BK_SHIFT;
        int pos = b * BCAP + ((src < SRC_SPLIT) ? atomicAdd(&scurLo[ln], 1)
                                                : atomicAdd(&scurHi[ln], 1));
        srcidx[pos] = src;
    }
}

// ---------- fused layer 1: gbounds + (Ahat*X) + h1s = fp16(ELU(.@W1+b1)*dis) ----------
__global__ void k_layer1(const float* __restrict__ xs, const int* __restrict__ offs,
                         const int* __restrict__ endp, const int* __restrict__ srcidx,
                         const float* __restrict__ dis, const int* __restrict__ batch,
                         const float* __restrict__ W1, const float* __restrict__ b1,
                         int* __restrict__ gstart, int* __restrict__ gend,
                         __half* __restrict__ h1s) {
    __shared__ float4 sagg[256];
    __shared__ float sdis[256];
    __shared__ float sW1[IN_DIM * N_HID];
    __shared__ float sb1[N_HID];
    int t = threadIdx.x;
    int nb = blockIdx.x * 256;
    int i = nb + t;
    sW1[t] = W1[t];                        // 256 = IN_DIM*N_HID
    if (t < N_HID) sb1[t] = b1[t];
    if (i < N_NODES) {
        int g = batch[i];
        if (i == 0 || batch[i - 1] != g) gstart[g] = i;          // no atomics:
        if (i == N_NODES - 1 || batch[i + 1] != g) gend[g] = i + 1;  // batch sorted
        const float4* xs4 = (const float4*)xs;
        float4 a0 = xs4[i];                // self-loop (xs = x*dis)
        float4 a1 = make_float4(0.f, 0.f, 0.f, 0.f);
        float4 a2 = a1, a3 = a1;
        int q = offs[i], e = endp[i];
        for (; q + 4 <= e; q += 4) {       // 4 independent gathers in flight
            int i0 = srcidx[q], i1 = srcidx[q + 1], i2 = srcidx[q + 2], i3 = srcidx[q + 3];
            float4 v0 = xs4[i0], v1 = xs4[i1], v2 = xs4[i2], v3 = xs4[i3];
            a0.x += v0.x; a0.y += v0.y; a0.z += v0.z; a0.w += v0.w;
            a1.x += v1.x; a1.y += v1.y; a1.z += v1.z; a1.w += v1.w;
            a2.x += v2.x; a2.y += v2.y; a2.z += v2.z; a2.w += v2.w;
            a3.x += v3.x; a3.y += v3.y; a3.z += v3.z; a3.w += v3.w;
        }
        for (; q < e; ++q) {
            float4 v = xs4[srcidx[q]];
            a0.x += v.x; a0.y += v.y; a0.z += v.z; a0.w += v.w;
        }
        float dd = dis[i];
        float4 r;
        r.x = (a0.x + a1.x + a2.x + a3.x) * dd;
        r.y = (a0.y + a1.y + a2.y + a3.y) * dd;
        r.z = (a0.z + a1.z + a2.z + a3.z) * dd;
        r.w = (a0.w + a1.w + a2.w + a3.w) * dd;
        sagg[t] = r;
        sdis[t] = dd;
    } else {
        sagg[t] = make_float4(0.f, 0.f, 0.f, 0.f);
        sdis[t] = 0.f;
    }
    __syncthreads();
    int w = t >> 6, j = t & 63;
    float w0 = sW1[0 * N_HID + j], w1 = sW1[1 * N_HID + j];
    float w2 = sW1[2 * N_HID + j], w3 = sW1[3 * N_HID + j];
    float bj = sb1[j];
    for (int n = 0; n < 64; ++n) {
        int local = w * 64 + n;
        int node = nb + local;
        if (node >= N_NODES) break;        // wave-uniform (j not involved)
        float4 a = sagg[local];            // LDS broadcast
        float acc = a.x * w0 + a.y * w1 + a.z * w2 + a.w * w3 + bj;
        acc = acc > 0.f ? acc : expm1f(acc);
        h1s[(size_t)node * N_HID + j] = __float2half_rn(acc * sdis[local]);
    }
}

// ---------- fp16 row-chunk accumulate: raw float4 = 8 halves -> 8 fp32 accs ----------
__device__ inline void acc_half8(float* acc, float4 raw) {
    const __half2* hp = (const __half2*)&raw;
#pragma unroll
    for (int c = 0; c < 4; ++c) {
        float2 f = __half22float2(hp[c]);
        acc[2 * c + 0] += f.x;
        acc[2 * c + 1] += f.y;
    }
}

// ---------- shared gather core: one wave per node over [start,end) ----------
// NOTE: every __shfl must be executed by ALL 64 lanes — ds_bpermute reads 0
// from EXEC-masked source lanes. Only the dependent load/add is predicated.
__device__ inline void gather_range(const float4* __restrict__ hsv,
                                    const int* __restrict__ srcidx,
                                    int start, int end, int lane, int g, int l,
                                    float* accA, float* accB) {
    for (int base = start; base < end; base += 64) {
        int nc = end - base; if (nc > 64) nc = 64;
        int myidx = (base + lane < end)
                        ? __builtin_nontemporal_load(&srcidx[base + lane]) : 0;
        int q = 0;
        for (; q + 16 <= nc; q += 16) {          // 2 loads (16 edges) in flight
            int s0 = __shfl(myidx, q + g);
            int s1 = __shfl(myidx, q + 8 + g);
            float4 r0 = hsv[(size_t)s0 * 8 + l];
            float4 r1 = hsv[(size_t)s1 * 8 + l];
            acc_half8(accA, r0);
            acc_half8(accB, r1);
        }
        if (q + 8 <= nc) {                       // full 8-edge step
            int s = __shfl(myidx, q + g);
            acc_half8(accA, hsv[(size_t)s * 8 + l]);
            q += 8;
        }
        {                                        // ragged tail (0-7 edges)
            int s = __shfl(myidx, q + g);        // ALL lanes execute (q+g <= 63)
            if (q + g < nc) acc_half8(accB, hsv[(size_t)s * 8 + l]);
        }
    }
}

__device__ inline void fold_groups(float* accA, const float* accB) {
#pragma unroll
    for (int c = 0; c < 8; ++c) accA[c] += accB[c];
#pragma unroll
    for (int c = 0; c < 8; ++c) {                // fold 8 group-partials
        accA[c] += __shfl_xor(accA[c], 8);
        accA[c] += __shfl_xor(accA[c], 16);
        accA[c] += __shfl_xor(accA[c], 32);
    }
}

// ---------- pass LO: src<25000 half-table (3.2 MB, L2-resident) -> raw partial ----
__global__ void k_agg_lo(const __half* __restrict__ h1s, const int* __restrict__ offs,
                         const int* __restrict__ mid, const int* __restrict__ srcidx,
                         float* __restrict__ tmp2) {
    int wid = (blockIdx.x * blockDim.x + threadIdx.x) >> 6;
    int lane = threadIdx.x & 63;
    int g = lane >> 3, l = lane & 7;
    if (wid >= N_NODES) return;
    const float4* hsv = (const float4*)h1s;
    float accA[8] = {0.f, 0.f, 0.f, 0.f, 0.f, 0.f, 0.f, 0.f};
    float accB[8] = {0.f, 0.f, 0.f, 0.f, 0.f, 0.f, 0.f, 0.f};
    gather_range(hsv, srcidx, offs[wid], mid[wid], lane, g, l, accA, accB);
    fold_groups(accA, accB);
    if (g == 0) {                                // lane l holds feats [8l,8l+8)
        nt_f4* t4 = (nt_f4*)tmp2;
        nt_f4 v0, v1;
        v0.x = accA[0]; v0.y = accA[1]; v0.z = accA[2]; v0.w = accA[3];
        v1.x = accA[4]; v1.y = accA[5]; v1.z = accA[6]; v1.w = accA[7];
        __builtin_nontemporal_store(v0, &t4[(size_t)wid * 16 + 2 * l]);
        __builtin_nontemporal_store(v1, &t4[(size_t)wid * 16 + 2 * l + 1]);
    }
}

// ---------- pass HI: src>=25000 half-table + self-loop + partial, x dis ----------
__global__ void k_agg_hi(const __half* __restrict__ h1s, const int* __restrict__ mid,
                         const int* __restrict__ endp, const int* __restrict__ srcidx,
                         const float* __restrict__ dis, float* __restrict__ tmp2) {
    int wid = (blockIdx.x * blockDim.x + threadIdx.x) >> 6;
    int lane = threadIdx.x & 63;
    int g = lane >> 3, l = lane & 7;
    if (wid >= N_NODES) return;
    const float4* hsv = (const float4*)h1s;
    float accA[8] = {0.f, 0.f, 0.f, 0.f, 0.f, 0.f, 0.f, 0.f};
    float accB[8] = {0.f, 0.f, 0.f, 0.f, 0.f, 0.f, 0.f, 0.f};
    if (g == 0) acc_half8(accA, hsv[(size_t)wid * 8 + l]);   // self-loop
    gather_range(hsv, srcidx, mid[wid], endp[wid], lane, g, l, accA, accB);
    fold_groups(accA, accB);
    if (g == 0) {
        nt_f4* t4 = (nt_f4*)tmp2;
        nt_f4 p0 = __builtin_nontemporal_load(&t4[(size_t)wid * 16 + 2 * l]);
        nt_f4 p1 = __builtin_nontemporal_load(&t4[(size_t)wid * 16 + 2 * l + 1]);
        float dw = dis[wid];
        nt_f4 v0, v1;
        v0.x = (accA[0] + p0.x) * dw; v0.y = (accA[1] + p0.y) * dw;
        v0.z = (accA[2] + p0.z) * dw; v0.w = (accA[3] + p0.w) * dw;
        v1.x = (accA[4] + p1.x) * dw; v1.y = (accA[5] + p1.y) * dw;
        v1.z = (accA[6] + p1.z) * dw; v1.w = (accA[7] + p1.w) * dw;
        __builtin_nontemporal_store(v0, &t4[(size_t)wid * 16 + 2 * l]);
        __builtin_nontemporal_store(v1, &t4[(size_t)wid * 16 + 2 * l + 1]);
    }
}

// ---------- GEMM + ELU + pool: 64 nodes/block, register-tiled, W2 via L1 ----------
#define GP_NODES 64
__global__ void k_gemmpool(const float* __restrict__ tmp2, const int* __restrict__ batch,
                           const float* __restrict__ W2, const float* __restrict__ b2,
                           float* __restrict__ sums) {
    __shared__ float sAT[N_HID][68];       // [k][n] tmp2, then [feat][n] h2
    __shared__ int sbat[GP_NODES];
    int t = threadIdx.x;  // 256
    int nb = blockIdx.x * GP_NODES;
    if (t < GP_NODES) sbat[t] = (nb + t < N_NODES) ? batch[nb + t] : -1;
    {   // stage tmp2 transposed: thread t -> node sn=t>>2, k-range (t&3)*16..+15
        int sn = t >> 2, k0 = (t & 3) * 16;
        int node = nb + sn;
        bool ok = node < N_NODES;
        const float4* a4 = (const float4*)&tmp2[(size_t)(ok ? node : 0) * N_HID];
#pragma unroll
        for (int i = 0; i < 4; ++i) {
            float4 v = ok ? a4[k0 / 4 + i] : make_float4(0.f, 0.f, 0.f, 0.f);
            sAT[k0 + 4 * i + 0][sn] = v.x;
            sAT[k0 + 4 * i + 1][sn] = v.y;
            sAT[k0 + 4 * i + 2][sn] = v.z;
            sAT[k0 + 4 * i + 3][sn] = v.w;
        }
    }
    __syncthreads();
    int tj = t & 15, tn = t >> 4;
    const float4* W2v = (const float4*)W2;   // 16 float4 per k-row (L1-resident)
    float4 acc0 = make_float4(0.f, 0.f, 0.f, 0.f);
    float4 acc1 = acc0, acc2 = acc0, acc3 = acc0;
#pragma unroll 8
    for (int k = 0; k < N_HID; ++k) {
        float4 a = *(const float4*)&sAT[k][4 * tn];
        float4 w = W2v[k * 16 + tj];
        acc0.x += a.x * w.x; acc0.y += a.x * w.y; acc0.z += a.x * w.z; acc0.w += a.x * w.w;
        acc1.x += a.y * w.x; acc1.y += a.y * w.y; acc1.z += a.y * w.z; acc1.w += a.y * w.w;
        acc2.x += a.z * w.x; acc2.y += a.z * w.y; acc2.z += a.z * w.z; acc2.w += a.z * w.w;
        acc3.x += a.w * w.x; acc3.y += a.w * w.y; acc3.z += a.w * w.z; acc3.w += a.w * w.w;
    }
    float4 bb = ((const float4*)b2)[tj];
    __syncthreads();   // everyone done reading sAT before overwrite
    // h2 back into sAT as [feat][node]
#define GP_WB(ACC, I)                                                         \
    {                                                                         \
        float4 r;                                                             \
        r.x = ACC.x + bb.x; r.y = ACC.y + bb.y;                               \
        r.z = ACC.z + bb.z; r.w = ACC.w + bb.w;                               \
        r.x = r.x > 0.f ? r.x : expm1f(r.x);                                  \
        r.y = r.y > 0.f ? r.y : expm1f(r.y);                                  \
        r.z = r.z > 0.f ? r.z : expm1f(r.z);                                  \
        r.w = r.w > 0.f ? r.w : expm1f(r.w);                                  \
        sAT[4 * tj + 0][4 * tn + (I)] = r.x;                                  \
        sAT[4 * tj + 1][4 * tn + (I)] = r.y;                                  \
        sAT[4 * tj + 2][4 * tn + (I)] = r.z;                                  \
        sAT[4 * tj + 3][4 * tn + (I)] = r.w;                                  \
    }
    GP_WB(acc0, 0) GP_WB(acc1, 1) GP_WB(acc2, 2) GP_WB(acc3, 3)
#undef GP_WB
    __syncthreads();
    // per-graph segment pooling (batch sorted; uniform flow; 4 waves)
    int j = t & 63, w = t >> 6;
    int s = 0;
    while (s < GP_NODES) {
        int gg = sbat[s];
        int e = s + 1;
        while (e < GP_NODES && sbat[e] == gg) ++e;
        if (gg >= 0 && s + w < e) {
            float p = 0.f;
            for (int n = s + w; n < e; n += 4) p += sAT[j][n];
            atomicAdd(&sums[gg * N_HID + j], p);
        }
        s = e;
    }
}

// ---------- final: out[g] = dot(sums[g]/cnt, W3) + b3 ; one wave per graph ----------
__global__ void k_final(const float* __restrict__ sums, const int* __restrict__ gstart,
                        const int* __restrict__ gend, const float* __restrict__ W3,
                        const float* __restrict__ b3, float* __restrict__ out) {
    int gid = blockIdx.x * 4 + (threadIdx.x >> 6);
    int j = threadIdx.x & 63;
    if (gid >= N_GRAPHS) return;
    int cnt = gend[gid] - gstart[gid];
    float v = sums[gid * N_HID + j] / (float)(cnt > 0 ? cnt : 1);
    float p = v * W3[j];
#pragma unroll
    for (int off = 32; off; off >>= 1) p += __shfl_down(p, off);
    if (j == 0) out[gid] = p + b3[0];
}

extern "C" void kernel_launch(void* const* d_in, const int* in_sizes, int n_in,
                              void* d_out, int out_size, void* d_ws, size_t ws_size,
                              hipStream_t stream) {
    const float* x   = (const float*)d_in[0];
    const int*   ei  = (const int*)d_in[1];
    const int*   bat = (const int*)d_in[2];
    const float* W1  = (const float*)d_in[3];
    const float* b1  = (const float*)d_in[4];
    const float* W2  = (const float*)d_in[5];
    const float* b2  = (const float*)d_in[6];
    const float* W3  = (const float*)d_in[7];
    const float* b3  = (const float*)d_in[8];
    float* out = (float*)d_out;

    // ---- workspace ----
    char* w = (char*)d_ws;
    int*   bcur   = (int*)w;   w += 512 * 4;
    int*   offs   = (int*)w;   w += NPAD * 4;
    int*   mid    = (int*)w;   w += NPAD * 4;
    int*   endp   = (int*)w;   w += NPAD * 4;
    float* dis    = (float*)w; w += NPAD * 4;
    int*   gstart = (int*)w;   w += 512 * 4;
    int*   gend   = (int*)w;   w += 512 * 4;
    float* sums   = (float*)w; w += (size_t)N_GRAPHS * N_HID * 4;  // 128 KB
    float* xs     = (float*)w; w += (size_t)NPAD * IN_DIM * 4;     // 800 KB
    int*   srcidx = (int*)w;   w += (size_t)NBUCK * BCAP * 4;      // 4.8 MB
    int*   P      = (int*)w;   w += (size_t)NBUCK * BCAP * 4;      // 4.8 MB
    __half* h1s   = (__half*)w; w += (size_t)N_NODES * N_HID * 2;  // 6.4 MB (fp16)
    float* tmp2   = (float*)w; w += (size_t)N_NODES * N_HID * 4;   // 12.8 MB

    const int B = 256;
    const int gN = (N_NODES + B - 1) / B;
    const int gW = (N_NODES * 64 + B - 1) / B;   // one wave per node

    k_init<<<(N_GRAPHS * N_HID + B - 1) / B, B, 0, stream>>>(bcur, gstart, gend, sums);
    k_bin<<<NWG_BIN, B, 0, stream>>>(ei, bcur, P);
    k_build<<<NBUCK, B, 0, stream>>>(bcur, P, x, srcidx, offs, mid, endp, dis, xs);

    // fused layer 1 (+ graph bounds), h1s stored fp16 (128B rows = 1 line/edge)
    k_layer1<<<gN, B, 0, stream>>>(xs, offs, endp, srcidx, dis, bat, W1, b1,
                                   gstart, gend, h1s);

    // layer 2: src-partitioned two-phase gather (each phase's table half is
    // L2-resident per XCD), then GEMM+ELU+pool
    k_agg_lo<<<gW, B, 0, stream>>>(h1s, offs, mid, srcidx, tmp2);
    k_agg_hi<<<gW, B, 0, stream>>>(h1s, mid, endp, srcidx, dis, tmp2);
    k_gemmpool<<<(N_NODES + GP_NODES - 1) / GP_NODES, B, 0, stream>>>(
        tmp2, bat, W2, b2, sums);

    k_final<<<(N_GRAPHS + 3) / 4, B, 0, stream>>>(sums, gstart, gend, W3, b3, out);
}

// Round 18
// 97.018 us; speedup vs baseline: 1.2250x; 1.2250x over previous
//
#include <hip/hip_runtime.h>
#include <hip/hip_fp16.h>
#include <math.h>

#define N_NODES 50000
#define N_EDGES 1000000
#define N_HID 64
#define N_GRAPHS 500
#define IN_DIM 4
#define NPAD 50048

#define BK_SHIFT 7
#define BK_NODES 128                      // nodes per bucket
#define NBUCK 391                         // ceil(50000/128)
#define BCAP 3072                         // mean 2560 + 10 sigma
#define EPT 16                            // edges per thread in k_bin
#define EPW (EPT * 256)                   // 4096 edges per WG
#define NWG_BIN ((N_EDGES + EPW - 1) / EPW)

// ---------- init: bcur + pooled sums (gstart/gend need no init: k_layer1
// writes every boundary; empty graphs have sums==0 -> out=b3 either way) ----------
__global__ void k_init(int* bcur, float* sums) {
    int i = blockIdx.x * blockDim.x + threadIdx.x;
    if (i < 512) bcur[i] = 0;
    if (i < N_GRAPHS * N_HID) sums[i] = 0.f;
}

// ---------- pass A: bin packed (src<<7|dstlocal) by dst bucket ----------
// single-histogram: pass-1 atomic return value IS the local offset.
__global__ void k_bin(const int* __restrict__ ei, int* bcur, int* __restrict__ P) {
    __shared__ int hist[NBUCK];
    __shared__ int base[NBUCK];
    int t = threadIdx.x;
    int wg0 = blockIdx.x * EPW;
    for (int b = t; b < NBUCK; b += 256) hist[b] = 0;
    __syncthreads();

    const int4* s4 = (const int4*)ei;
    const int4* d4 = (const int4*)(ei + N_EDGES);
    int rs[EPT], rd[EPT], rl[EPT];
#pragma unroll
    for (int i = 0; i < 4; ++i) {
        int e = wg0 + (i * 256 + t) * 4;
        if (e < N_EDGES) {
            int4 vs = s4[e >> 2];
            int4 vd = d4[e >> 2];
            rs[i * 4 + 0] = vs.x; rd[i * 4 + 0] = vd.x;
            rs[i * 4 + 1] = vs.y; rd[i * 4 + 1] = vd.y;
            rs[i * 4 + 2] = vs.z; rd[i * 4 + 2] = vd.z;
            rs[i * 4 + 3] = vs.w; rd[i * 4 + 3] = vd.w;
            rl[i * 4 + 0] = atomicAdd(&hist[vd.x >> BK_SHIFT], 1);
            rl[i * 4 + 1] = atomicAdd(&hist[vd.y >> BK_SHIFT], 1);
            rl[i * 4 + 2] = atomicAdd(&hist[vd.z >> BK_SHIFT], 1);
            rl[i * 4 + 3] = atomicAdd(&hist[vd.w >> BK_SHIFT], 1);
        } else {
            rd[i * 4 + 0] = rd[i * 4 + 1] = rd[i * 4 + 2] = rd[i * 4 + 3] = -1;
        }
    }
    __syncthreads();
    for (int b = t; b < NBUCK; b += 256) {
        int h = hist[b];
        base[b] = h ? atomicAdd(&bcur[b], h) : 0;
    }
    __syncthreads();
#pragma unroll
    for (int i = 0; i < EPT; ++i) {
        if (rd[i] >= 0) {
            int bk = rd[i] >> BK_SHIFT;
            int loc = base[bk] + rl[i];
            if (loc > BCAP - 1) loc = BCAP - 1;   // overflow guard (never expected)
            P[(size_t)bk * BCAP + loc] = (rs[i] << BK_SHIFT) | (rd[i] & (BK_NODES - 1));
        }
    }
}

// ---------- pass B: per-bucket counting sort -> CSR rows + dis + xs=x*dis ----------
__global__ void k_build(const int* __restrict__ bcur, const int* __restrict__ P,
                        const float* __restrict__ x,
                        int* __restrict__ srcidx, int* __restrict__ offs,
                        int* __restrict__ endp, float* __restrict__ dis,
                        float* __restrict__ xs) {
    __shared__ int sp[BCAP];
    __shared__ int scnt[BK_NODES];
    __shared__ int sscan[BK_NODES];
    __shared__ int scur[BK_NODES];
    int b = blockIdx.x;
    int t = threadIdx.x;
    int n = bcur[b];
    if (n > BCAP) n = BCAP;
    if (t < BK_NODES) scnt[t] = 0;
    __syncthreads();
    for (int i = t; i < n; i += 256) {
        int v = P[(size_t)b * BCAP + i];
        sp[i] = v;
        atomicAdd(&scnt[v & (BK_NODES - 1)], 1);
    }
    __syncthreads();
    if (t < BK_NODES) sscan[t] = scnt[t];
    __syncthreads();
    for (int d = 1; d < BK_NODES; d <<= 1) {
        int v = 0;
        if (t < BK_NODES && t >= d) v = sscan[t - d];
        __syncthreads();
        if (t < BK_NODES) sscan[t] += v;
        __syncthreads();
    }
    if (t < BK_NODES) {
        int excl = sscan[t] - scnt[t];
        scur[t] = excl;
        int node = b * BK_NODES + t;
        if (node < N_NODES) {
            int o = b * BCAP + excl;
            offs[node] = o;
            endp[node] = o + scnt[t];
            float dd = 1.0f / sqrtf((float)(scnt[t] + 1));
            dis[node] = dd;
            float4 xv = ((const float4*)x)[node];
            xv.x *= dd; xv.y *= dd; xv.z *= dd; xv.w *= dd;
            ((float4*)xs)[node] = xv;
        }
    }
    __syncthreads();
    for (int i = t; i < n; i += 256) {
        int v = sp[i];
        int ln = v & (BK_NODES - 1);
        int pos = b * BCAP + atomicAdd(&scur[ln], 1);
        srcidx[pos] = v >> BK_SHIFT;
    }
}

// ---------- fused layer 1: gbounds + (Ahat*X) + h1s = fp16(ELU(.@W1+b1)*dis) ----------
__global__ void k_layer1(const float* __restrict__ xs, const int* __restrict__ offs,
                         const int* __restrict__ endp, const int* __restrict__ srcidx,
                         const float* __restrict__ dis, const int* __restrict__ batch,
                         const float* __restrict__ W1, const float* __restrict__ b1,
                         int* __restrict__ gstart, int* __restrict__ gend,
                         __half* __restrict__ h1s) {
    __shared__ float4 sagg[256];
    __shared__ float sdis[256];
    __shared__ float sW1[IN_DIM * N_HID];
    __shared__ float sb1[N_HID];
    int t = threadIdx.x;
    int nb = blockIdx.x * 256;
    int i = nb + t;
    sW1[t] = W1[t];                        // 256 = IN_DIM*N_HID
    if (t < N_HID) sb1[t] = b1[t];
    if (i < N_NODES) {
        int g = batch[i];
        if (i == 0 || batch[i - 1] != g) gstart[g] = i;          // no atomics:
        if (i == N_NODES - 1 || batch[i + 1] != g) gend[g] = i + 1;  // batch sorted
        const float4* xs4 = (const float4*)xs;
        float4 a0 = xs4[i];                // self-loop (xs = x*dis)
        float4 a1 = make_float4(0.f, 0.f, 0.f, 0.f);
        float4 a2 = a1, a3 = a1;
        int q = offs[i], e = endp[i];
        for (; q + 4 <= e; q += 4) {       // 4 independent gathers in flight
            int i0 = srcidx[q], i1 = srcidx[q + 1], i2 = srcidx[q + 2], i3 = srcidx[q + 3];
            float4 v0 = xs4[i0], v1 = xs4[i1], v2 = xs4[i2], v3 = xs4[i3];
            a0.x += v0.x; a0.y += v0.y; a0.z += v0.z; a0.w += v0.w;
            a1.x += v1.x; a1.y += v1.y; a1.z += v1.z; a1.w += v1.w;
            a2.x += v2.x; a2.y += v2.y; a2.z += v2.z; a2.w += v2.w;
            a3.x += v3.x; a3.y += v3.y; a3.z += v3.z; a3.w += v3.w;
        }
        for (; q < e; ++q) {
            float4 v = xs4[srcidx[q]];
            a0.x += v.x; a0.y += v.y; a0.z += v.z; a0.w += v.w;
        }
        float dd = dis[i];
        float4 r;
        r.x = (a0.x + a1.x + a2.x + a3.x) * dd;
        r.y = (a0.y + a1.y + a2.y + a3.y) * dd;
        r.z = (a0.z + a1.z + a2.z + a3.z) * dd;
        r.w = (a0.w + a1.w + a2.w + a3.w) * dd;
        sagg[t] = r;
        sdis[t] = dd;
    } else {
        sagg[t] = make_float4(0.f, 0.f, 0.f, 0.f);
        sdis[t] = 0.f;
    }
    __syncthreads();
    int w = t >> 6, j = t & 63;
    float w0 = sW1[0 * N_HID + j], w1 = sW1[1 * N_HID + j];
    float w2 = sW1[2 * N_HID + j], w3 = sW1[3 * N_HID + j];
    float bj = sb1[j];
    for (int n = 0; n < 64; ++n) {
        int local = w * 64 + n;
        int node = nb + local;
        if (node >= N_NODES) break;        // wave-uniform (j not involved)
        float4 a = sagg[local];            // LDS broadcast
        float acc = a.x * w0 + a.y * w1 + a.z * w2 + a.w * w3 + bj;
        acc = acc > 0.f ? acc : expm1f(acc);
        h1s[(size_t)node * N_HID + j] = __float2half_rn(acc * sdis[local]);
    }
}

// ---------- fp16 row-chunk accumulate: raw float4 = 8 halves -> 8 fp32 accs ----------
__device__ inline void acc_half8(float* acc, float4 raw) {
    const __half2* hp = (const __half2*)&raw;
#pragma unroll
    for (int c = 0; c < 4; ++c) {
        float2 f = __half22float2(hp[c]);
        acc[2 * c + 0] += f.x;
        acc[2 * c + 1] += f.y;
    }
}

// ---------- standalone agg: one wave per node, fp16 gather, NO barriers ----------
// fp16 row = 128 B = exactly 1 cache line per edge. Measured floor: ~30 us for
// 1M random line-gathers (~4.3 TB/s effective). Levers tested and falsified:
// occupancy (r12), bytes (r13 helped, capped), ILP depth (r15), cache-tier
// phasing (r14 feature-split, r17 src-split).
// NOTE: every __shfl must be executed by ALL 64 lanes — ds_bpermute reads 0
// from EXEC-masked source lanes. Only the dependent load/add is predicated.
__global__ void k_agg16(const __half* __restrict__ h1s, const int* __restrict__ offs,
                        const int* __restrict__ endp, const int* __restrict__ srcidx,
                        const float* __restrict__ dis, float* __restrict__ tmp2) {
    int wid = (blockIdx.x * blockDim.x + threadIdx.x) >> 6;
    int lane = threadIdx.x & 63;
    int g = lane >> 3, l = lane & 7;             // 8 groups x 8 lanes
    if (wid >= N_NODES) return;
    const float4* hsv = (const float4*)h1s;      // 8 float4 per 128B row
    float accA[8] = {0.f, 0.f, 0.f, 0.f, 0.f, 0.f, 0.f, 0.f};
    float accB[8] = {0.f, 0.f, 0.f, 0.f, 0.f, 0.f, 0.f, 0.f};
    if (g == 0) acc_half8(accA, hsv[(size_t)wid * 8 + l]);   // self-loop
    int start = offs[wid], end = endp[wid];
    for (int base = start; base < end; base += 64) {
        int nc = end - base; if (nc > 64) nc = 64;
        int myidx = (base + lane < end) ? srcidx[base + lane] : 0;
        int q = 0;
        for (; q + 16 <= nc; q += 16) {          // 2 loads (16 edges) in flight
            int s0 = __shfl(myidx, q + g);
            int s1 = __shfl(myidx, q + 8 + g);
            float4 r0 = hsv[(size_t)s0 * 8 + l];
            float4 r1 = hsv[(size_t)s1 * 8 + l];
            acc_half8(accA, r0);
            acc_half8(accB, r1);
        }
        if (q + 8 <= nc) {                       // full 8-edge step
            int s = __shfl(myidx, q + g);
            acc_half8(accA, hsv[(size_t)s * 8 + l]);
            q += 8;
        }
        {                                        // ragged tail (0-7 edges)
            int s = __shfl(myidx, q + g);        // ALL lanes execute (q+g <= 63)
            if (q + g < nc) acc_half8(accB, hsv[(size_t)s * 8 + l]);
        }
    }
#pragma unroll
    for (int c = 0; c < 8; ++c) accA[c] += accB[c];
#pragma unroll
    for (int c = 0; c < 8; ++c) {                // fold 8 group-partials
        accA[c] += __shfl_xor(accA[c], 8);
        accA[c] += __shfl_xor(accA[c], 16);
        accA[c] += __shfl_xor(accA[c], 32);
    }
    if (g == 0) {                                // lane l holds feats [8l,8l+8)
        float dw = dis[wid];
        float4 v0 = make_float4(accA[0] * dw, accA[1] * dw, accA[2] * dw, accA[3] * dw);
        float4 v1 = make_float4(accA[4] * dw, accA[5] * dw, accA[6] * dw, accA[7] * dw);
        ((float4*)tmp2)[(size_t)wid * 16 + 2 * l] = v0;
        ((float4*)tmp2)[(size_t)wid * 16 + 2 * l + 1] = v1;
    }
}

// ---------- GEMM + ELU + pool: 64 nodes/block, register-tiled, W2 via L1 ----------
#define GP_NODES 64
__global__ void k_gemmpool(const float* __restrict__ tmp2, const int* __restrict__ batch,
                           const float* __restrict__ W2, const float* __restrict__ b2,
                           float* __restrict__ sums) {
    __shared__ float sAT[N_HID][68];       // [k][n] tmp2, then [feat][n] h2
    __shared__ int sbat[GP_NODES];
    int t = threadIdx.x;  // 256
    int nb = blockIdx.x * GP_NODES;
    if (t < GP_NODES) sbat[t] = (nb + t < N_NODES) ? batch[nb + t] : -1;
    {   // stage tmp2 transposed: thread t -> node sn=t>>2, k-range (t&3)*16..+15
        int sn = t >> 2, k0 = (t & 3) * 16;
        int node = nb + sn;
        bool ok = node < N_NODES;
        const float4* a4 = (const float4*)&tmp2[(size_t)(ok ? node : 0) * N_HID];
#pragma unroll
        for (int i = 0; i < 4; ++i) {
            float4 v = ok ? a4[k0 / 4 + i] : make_float4(0.f, 0.f, 0.f, 0.f);
            sAT[k0 + 4 * i + 0][sn] = v.x;
            sAT[k0 + 4 * i + 1][sn] = v.y;
            sAT[k0 + 4 * i + 2][sn] = v.z;
            sAT[k0 + 4 * i + 3][sn] = v.w;
        }
    }
    __syncthreads();
    int tj = t & 15, tn = t >> 4;
    const float4* W2v = (const float4*)W2;   // 16 float4 per k-row (L1-resident)
    float4 acc0 = make_float4(0.f, 0.f, 0.f, 0.f);
    float4 acc1 = acc0, acc2 = acc0, acc3 = acc0;
#pragma unroll 8
    for (int k = 0; k < N_HID; ++k) {
        float4 a = *(const float4*)&sAT[k][4 * tn];
        float4 w = W2v[k * 16 + tj];
        acc0.x += a.x * w.x; acc0.y += a.x * w.y; acc0.z += a.x * w.z; acc0.w += a.x * w.w;
        acc1.x += a.y * w.x; acc1.y += a.y * w.y; acc1.z += a.y * w.z; acc1.w += a.y * w.w;
        acc2.x += a.z * w.x; acc2.y += a.z * w.y; acc2.z += a.z * w.z; acc2.w += a.z * w.w;
        acc3.x += a.w * w.x; acc3.y += a.w * w.y; acc3.z += a.w * w.z; acc3.w += a.w * w.w;
    }
    float4 bb = ((const float4*)b2)[tj];
    __syncthreads();   // everyone done reading sAT before overwrite
    // h2 back into sAT as [feat][node]
#define GP_WB(ACC, I)                                                         \
    {                                                                         \
        float4 r;                                                             \
        r.x = ACC.x + bb.x; r.y = ACC.y + bb.y;                               \
        r.z = ACC.z + bb.z; r.w = ACC.w + bb.w;                               \
        r.x = r.x > 0.f ? r.x : expm1f(r.x);                                  \
        r.y = r.y > 0.f ? r.y : expm1f(r.y);                                  \
        r.z = r.z > 0.f ? r.z : expm1f(r.z);                                  \
        r.w = r.w > 0.f ? r.w : expm1f(r.w);                                  \
        sAT[4 * tj + 0][4 * tn + (I)] = r.x;                                  \
        sAT[4 * tj + 1][4 * tn + (I)] = r.y;                                  \
        sAT[4 * tj + 2][4 * tn + (I)] = r.z;                                  \
        sAT[4 * tj + 3][4 * tn + (I)] = r.w;                                  \
    }
    GP_WB(acc0, 0) GP_WB(acc1, 1) GP_WB(acc2, 2) GP_WB(acc3, 3)
#undef GP_WB
    __syncthreads();
    // per-graph segment pooling (batch sorted; uniform flow; 4 waves)
    int j = t & 63, w = t >> 6;
    int s = 0;
    while (s < GP_NODES) {
        int gg = sbat[s];
        int e = s + 1;
        while (e < GP_NODES && sbat[e] == gg) ++e;
        if (gg >= 0 && s + w < e) {
            float p = 0.f;
            for (int n = s + w; n < e; n += 4) p += sAT[j][n];
            atomicAdd(&sums[gg * N_HID + j], p);
        }
        s = e;
    }
}

// ---------- final: out[g] = dot(sums[g]/cnt, W3) + b3 ; one wave per graph ----------
__global__ void k_final(const float* __restrict__ sums, const int* __restrict__ gstart,
                        const int* __restrict__ gend, const float* __restrict__ W3,
                        const float* __restrict__ b3, float* __restrict__ out) {
    int gid = blockIdx.x * 4 + (threadIdx.x >> 6);
    int j = threadIdx.x & 63;
    if (gid >= N_GRAPHS) return;
    int cnt = gend[gid] - gstart[gid];
    float v = sums[gid * N_HID + j] / (float)(cnt > 0 ? cnt : 1);
    float p = v * W3[j];
#pragma unroll
    for (int off = 32; off; off >>= 1) p += __shfl_down(p, off);
    if (j == 0) out[gid] = p + b3[0];
}

extern "C" void kernel_launch(void* const* d_in, const int* in_sizes, int n_in,
                              void* d_out, int out_size, void* d_ws, size_t ws_size,
                              hipStream_t stream) {
    const float* x   = (const float*)d_in[0];
    const int*   ei  = (const int*)d_in[1];
    const int*   bat = (const int*)d_in[2];
    const float* W1  = (const float*)d_in[3];
    const float* b1  = (const float*)d_in[4];
    const float* W2  = (const float*)d_in[5];
    const float* b2  = (const float*)d_in[6];
    const float* W3  = (const float*)d_in[7];
    const float* b3  = (const float*)d_in[8];
    float* out = (float*)d_out;

    // ---- workspace ----
    char* w = (char*)d_ws;
    int*   bcur   = (int*)w;   w += 512 * 4;
    int*   offs   = (int*)w;   w += NPAD * 4;
    int*   endp   = (int*)w;   w += NPAD * 4;
    float* dis    = (float*)w; w += NPAD * 4;
    int*   gstart = (int*)w;   w += 512 * 4;
    int*   gend   = (int*)w;   w += 512 * 4;
    float* sums   = (float*)w; w += (size_t)N_GRAPHS * N_HID * 4;  // 128 KB
    float* xs     = (float*)w; w += (size_t)NPAD * IN_DIM * 4;     // 800 KB
    int*   srcidx = (int*)w;   w += (size_t)NBUCK * BCAP * 4;      // 4.8 MB
    int*   P      = (int*)w;   w += (size_t)NBUCK * BCAP * 4;      // 4.8 MB
    __half* h1s   = (__half*)w; w += (size_t)N_NODES * N_HID * 2;  // 6.4 MB (fp16)
    float* tmp2   = (float*)w; w += (size_t)N_NODES * N_HID * 4;   // 12.8 MB

    const int B = 256;
    const int gN = (N_NODES + B - 1) / B;
    const int gW = (N_NODES * 64 + B - 1) / B;   // one wave per node

    k_init<<<(N_GRAPHS * N_HID + B - 1) / B, B, 0, stream>>>(bcur, sums);
    k_bin<<<NWG_BIN, B, 0, stream>>>(ei, bcur, P);
    k_build<<<NBUCK, B, 0, stream>>>(bcur, P, x, srcidx, offs, endp, dis, xs);

    // fused layer 1 (+ graph bounds), h1s stored fp16 (128B rows = 1 line/edge)
    k_layer1<<<gN, B, 0, stream>>>(xs, offs, endp, srcidx, dis, bat, W1, b1,
                                   gstart, gend, h1s);

    // layer 2, de-fused: free-running gather -> GEMM+ELU+pool
    k_agg16<<<gW, B, 0, stream>>>(h1s, offs, endp, srcidx, dis, tmp2);
    k_gemmpool<<<(N_NODES + GP_NODES - 1) / GP_NODES, B, 0, stream>>>(
        tmp2, bat, W2, b2, sums);

    k_final<<<(N_GRAPHS + 3) / 4, B, 0, stream>>>(sums, gstart, gend, W3, b3, out);
}